// Round 4
// baseline (188.241 us; speedup 1.0000x reference)
//
#include <hip/hip_runtime.h>

// Ultimus: out = x + softmax((x@Kw+Kb)@(x@Qw+Qb)^T / sqrt(8)) @ (x@Vw+Vb) @ Zw + Zb
// N=8192, D_IN=48, D_ATTN=8, fp32 in/out.
//
// R4 design (R3 + type fixes):
//  - Bound-softmax (Cauchy-Schwarz row bound) => fixed per-row exponent shift,
//    partial (acc,l) over disjoint j-chunks combine by pure addition.
//  - attn waves are fully independent: no LDS, no __syncthreads in the hot
//    loop. Lane L streams its own j's (q,v) global->VGPR, coalesced 32B/lane,
//    operands L2-resident (768 KB).
//  - f16 storage + v_dot2_f32_f16 (fdot2): QK dot, l-sum, and p*v accumulate
//    all as 2-way f16 dots with fp32 accumulators.
//
// ws layout (floats):
//   [0, 32768)        Xksf16[8192]  row-major, 8 f16/row (k * log2e/sqrt(8))
//   [32768, 65536)    Qf16[8192]    row-major, 8 f16/row
//   [65536, 98304)    Vf16          pair-interleaved: pair p=(j=2p,2p+1),
//                                   dword (p*8+c) = half2(V[2p][c], V[2p+1][c])
//   [98304]           qmax2 bits    max_j ||q_j||^2 fp32 (uint-bits atomicMax)
//   [98560, +786432)  part[8][8192][12]  per-chunk partials acc[0:8], l at [8]

#define PART_OFF 98560

typedef _Float16 f16x2 __attribute__((ext_vector_type(2)));

union HU { unsigned u; f16x2 h; };

static __device__ __forceinline__ unsigned pku(float a, float b) {
    auto v = __builtin_amdgcn_cvt_pkrtz(a, b);   // __fp16 vec2
    union { decltype(v) v2; unsigned u; } t;
    t.v2 = v;
    return t.u;
}
static __device__ __forceinline__ f16x2 asH2(unsigned u) {
    HU t; t.u = u; return t.h;
}
static __device__ __forceinline__ float fdot2(f16x2 a, f16x2 b, float c) {
#if __has_builtin(__builtin_amdgcn_fdot2)
    return __builtin_amdgcn_fdot2(a, b, c, false);
#else
    return fmaf((float)a.x, (float)b.x, fmaf((float)a.y, (float)b.y, c));
#endif
}

__global__ __launch_bounds__(256) void proj_kernel(
    const float* __restrict__ x,
    const float* __restrict__ Kw, const float* __restrict__ Kb,
    const float* __restrict__ Qw, const float* __restrict__ Qb,
    const float* __restrict__ Vw, const float* __restrict__ Vb,
    unsigned* __restrict__ Xksf16, unsigned* __restrict__ Qf16,
    unsigned* __restrict__ Vf16, unsigned int* __restrict__ qmax2_bits)
{
    __shared__ float xs[32 * 49];     // +1 pad
    __shared__ float wAll[3 * 388];   // stride 388 (mod 32 = 4) spreads 3 mats
    __shared__ float bs[24];
    __shared__ float outv[32][25];    // 24 cols + pad
    const int tid = threadIdx.x;
    const int r0 = blockIdx.x * 32;

    for (int i = tid; i < 1536; i += 256) {
        int r = i / 48, c = i - r * 48;
        xs[r * 49 + c] = x[r0 * 48 + i];
    }
    for (int i = tid; i < 384; i += 256) {
        wAll[i]       = Kw[i];
        wAll[388 + i] = Qw[i];
        wAll[776 + i] = Vw[i];
    }
    if (tid < 8)       bs[tid] = Kb[tid];
    else if (tid < 16) bs[tid] = Qb[tid - 8];
    else if (tid < 24) bs[tid] = Vb[tid - 16];
    __syncthreads();

    // thread = (row rl, col-group g): cols 3g..3g+2 of row r0+rl
    const int rl = tid >> 3;
    const int g  = tid & 7;
    const int c0 = 3 * g;
    const float* xr = &xs[rl * 49];
    const float* w0 = &wAll[((c0 + 0) >> 3) * 388 + ((c0 + 0) & 7)];
    const float* w1 = &wAll[((c0 + 1) >> 3) * 388 + ((c0 + 1) & 7)];
    const float* w2 = &wAll[((c0 + 2) >> 3) * 388 + ((c0 + 2) & 7)];
    float a0 = bs[c0], a1 = bs[c0 + 1], a2 = bs[c0 + 2];
    #pragma unroll
    for (int k = 0; k < 48; k++) {
        const float xv = xr[k];
        a0 = fmaf(xv, w0[k * 8], a0);
        a1 = fmaf(xv, w1[k * 8], a1);
        a2 = fmaf(xv, w2[k * 8], a2);
    }
    outv[rl][c0] = a0; outv[rl][c0 + 1] = a1; outv[rl][c0 + 2] = a2;
    __syncthreads();

    const float kscale = 0.51008732149f;  // (1/sqrt(8)) * log2(e)
    if (tid < 32) {                       // K rows, f16 packed, pre-scaled
        uint4 o;
        o.x = pku(outv[tid][0] * kscale, outv[tid][1] * kscale);
        o.y = pku(outv[tid][2] * kscale, outv[tid][3] * kscale);
        o.z = pku(outv[tid][4] * kscale, outv[tid][5] * kscale);
        o.w = pku(outv[tid][6] * kscale, outv[tid][7] * kscale);
        ((uint4*)Xksf16)[r0 + tid] = o;
    } else if (tid < 64) {                // Q rows, f16 packed
        const int r = tid - 32;
        uint4 o;
        o.x = pku(outv[r][8],  outv[r][9]);
        o.y = pku(outv[r][10], outv[r][11]);
        o.z = pku(outv[r][12], outv[r][13]);
        o.w = pku(outv[r][14], outv[r][15]);
        ((uint4*)Qf16)[r0 + r] = o;
    } else if (tid < 192) {               // V pair-interleaved
        const int t2 = tid - 64;
        const int p = t2 >> 3, c = t2 & 7;
        Vf16[(blockIdx.x * 16 + p) * 8 + c] =
            pku(outv[2 * p][16 + c], outv[2 * p + 1][16 + c]);
    } else if (tid < 224) {               // qmax over fp32 q (lanes 0..31 of wave 3)
        const int r = tid - 192;
        float n2 = 0.f;
        #pragma unroll
        for (int c = 0; c < 8; c++) n2 = fmaf(outv[r][8 + c], outv[r][8 + c], n2);
        #pragma unroll
        for (int off = 16; off > 0; off >>= 1)
            n2 = fmaxf(n2, __shfl_xor(n2, off, 64));
        if (r == 0) atomicMax(qmax2_bits, __float_as_uint(n2));  // n2>=0: bit order ok
    }
}

__global__ __launch_bounds__(256, 4) void attn_kernel(
    const unsigned* __restrict__ Xksf16, const unsigned* __restrict__ Qf16,
    const unsigned* __restrict__ Vf16,
    const unsigned int* __restrict__ qmax2_bits,
    float* __restrict__ part)
{
    const int tid   = threadIdx.x;
    const int wave  = tid >> 6, lane = tid & 63;
    const int rg    = blockIdx.x & 255;   // 32-row group
    const int chunk = blockIdx.x >> 8;    // j-chunk of 1024 (8 chunks)
    const int rw0   = rg * 32 + wave * 8;

    const float qmax2 = __uint_as_float(*qmax2_bits);

    f16x2 k2[8][4];
    float sinit[8], l[8], acc[8][8];
    #pragma unroll
    for (int r = 0; r < 8; r++) {
        const uint4 kv = ((const uint4*)Xksf16)[rw0 + r];
        k2[r][0] = asH2(kv.x); k2[r][1] = asH2(kv.y);
        k2[r][2] = asH2(kv.z); k2[r][3] = asH2(kv.w);
        float kn2 = fdot2(k2[r][0], k2[r][0], 0.f);
        kn2 = fdot2(k2[r][1], k2[r][1], kn2);
        kn2 = fdot2(k2[r][2], k2[r][2], kn2);
        kn2 = fdot2(k2[r][3], k2[r][3], kn2);
        sinit[r] = -sqrtf(kn2 * qmax2);   // |s| <= ||k_r||*max||q||: p in (0,~1]
        l[r] = 0.f;
        #pragma unroll
        for (int c = 0; c < 8; c++) acc[r][c] = 0.f;
    }

    const f16x2 one2 = asH2(pku(1.f, 1.f));
    const uint4* Q4 = (const uint4*)Qf16;   // idx = j
    const uint4* V4 = (const uint4*)Vf16;   // pair p -> uint4 idx 2p, 2p+1

    const int P0 = chunk * 512 + lane;      // this lane's first j-pair
    #pragma unroll 2
    for (int s = 0; s < 8; s++) {
        const int p = P0 + s * 64;
        const uint4 qa = Q4[2 * p];
        const uint4 qb = Q4[2 * p + 1];
        const uint4 va = V4[2 * p];
        const uint4 vb = V4[2 * p + 1];
        f16x2 qa2[4] = {asH2(qa.x), asH2(qa.y), asH2(qa.z), asH2(qa.w)};
        f16x2 qb2[4] = {asH2(qb.x), asH2(qb.y), asH2(qb.z), asH2(qb.w)};
        f16x2 v2[8]  = {asH2(va.x), asH2(va.y), asH2(va.z), asH2(va.w),
                        asH2(vb.x), asH2(vb.y), asH2(vb.z), asH2(vb.w)};
        #pragma unroll
        for (int r = 0; r < 8; r++) {
            float s0 = fdot2(k2[r][0], qa2[0], sinit[r]);
            s0 = fdot2(k2[r][1], qa2[1], s0);
            s0 = fdot2(k2[r][2], qa2[2], s0);
            s0 = fdot2(k2[r][3], qa2[3], s0);
            float s1 = fdot2(k2[r][0], qb2[0], sinit[r]);
            s1 = fdot2(k2[r][1], qb2[1], s1);
            s1 = fdot2(k2[r][2], qb2[2], s1);
            s1 = fdot2(k2[r][3], qb2[3], s1);
            const f16x2 ph = asH2(pku(__builtin_amdgcn_exp2f(s0),
                                      __builtin_amdgcn_exp2f(s1)));
            l[r] = fdot2(ph, one2, l[r]);
            acc[r][0] = fdot2(ph, v2[0], acc[r][0]);
            acc[r][1] = fdot2(ph, v2[1], acc[r][1]);
            acc[r][2] = fdot2(ph, v2[2], acc[r][2]);
            acc[r][3] = fdot2(ph, v2[3], acc[r][3]);
            acc[r][4] = fdot2(ph, v2[4], acc[r][4]);
            acc[r][5] = fdot2(ph, v2[5], acc[r][5]);
            acc[r][6] = fdot2(ph, v2[6], acc[r][6]);
            acc[r][7] = fdot2(ph, v2[7], acc[r][7]);
        }
    }

    // 64-lane butterfly sum; shared per-row exponent => pure adds
    #pragma unroll
    for (int m = 1; m < 64; m <<= 1) {
        #pragma unroll
        for (int r = 0; r < 8; r++) {
            l[r] += __shfl_xor(l[r], m, 64);
            #pragma unroll
            for (int c = 0; c < 8; c++) acc[r][c] += __shfl_xor(acc[r][c], m, 64);
        }
    }
    if (lane == 0) {
        float* pr = part + ((size_t)chunk * 8192 + rw0) * 12;
        #pragma unroll
        for (int r = 0; r < 8; r++) {
            #pragma unroll
            for (int c = 0; c < 8; c++) pr[r * 12 + c] = acc[r][c];
            pr[r * 12 + 8] = l[r];
        }
    }
}

__global__ __launch_bounds__(256) void finish_kernel(
    const float* __restrict__ x,
    const float* __restrict__ Zw, const float* __restrict__ Zb,
    const float* __restrict__ part, float* __restrict__ out)
{
    __shared__ float Zs[128 * 9];
    __shared__ float zw_s[384];
    __shared__ float zb_s[48];
    const int tid = threadIdx.x;
    const int r0 = blockIdx.x * 128;

    for (int i = tid; i < 384; i += 256) zw_s[i] = Zw[i];
    if (tid < 48) zb_s[tid] = Zb[tid];

    if (tid < 128) {
        const int row = r0 + tid;
        float a[9];
        #pragma unroll
        for (int c = 0; c < 9; c++) a[c] = 0.f;
        #pragma unroll
        for (int ch = 0; ch < 8; ch++) {
            const float* p = part + ((size_t)ch * 8192 + row) * 12;
            #pragma unroll
            for (int c = 0; c < 9; c++) a[c] += p[c];
        }
        const float inv = 1.0f / a[8];
        #pragma unroll
        for (int c = 0; c < 8; c++) Zs[tid * 9 + c] = a[c] * inv;
    }
    __syncthreads();

    for (int e = tid; e < 128 * 48; e += 256) {
        const int r = e / 48, c = e - r * 48;
        float o = x[r0 * 48 + e] + zb_s[c];
        #pragma unroll
        for (int k = 0; k < 8; k++) o = fmaf(Zs[r * 9 + k], zw_s[k * 48 + c], o);
        out[r0 * 48 + e] = o;
    }
}

extern "C" void kernel_launch(void* const* d_in, const int* in_sizes, int n_in,
                              void* d_out, int out_size, void* d_ws, size_t ws_size,
                              hipStream_t stream) {
    const float* x  = (const float*)d_in[0];
    const float* Kw = (const float*)d_in[1];
    const float* Kb = (const float*)d_in[2];
    const float* Qw = (const float*)d_in[3];
    const float* Qb = (const float*)d_in[4];
    const float* Vw = (const float*)d_in[5];
    const float* Vb = (const float*)d_in[6];
    const float* Zw = (const float*)d_in[7];
    const float* Zb = (const float*)d_in[8];
    float* out = (float*)d_out;

    float* ws = (float*)d_ws;
    unsigned* Xksf16 = (unsigned*)ws;
    unsigned* Qf16   = (unsigned*)(ws + 32768);
    unsigned* Vf16   = (unsigned*)(ws + 65536);
    unsigned int* qmax2_bits = (unsigned int*)(ws + 98304);
    float* part = ws + PART_OFF;

    (void)hipMemsetAsync(qmax2_bits, 0, sizeof(unsigned int), stream);
    proj_kernel<<<256, 256, 0, stream>>>(x, Kw, Kb, Qw, Qb, Vw, Vb,
                                         Xksf16, Qf16, Vf16, qmax2_bits);
    attn_kernel<<<2048, 256, 0, stream>>>(Xksf16, Qf16, Vf16, qmax2_bits, part);
    finish_kernel<<<64, 256, 0, stream>>>(x, Zw, Zb, part, out);
}

// Round 5
// 131.628 us; speedup vs baseline: 1.4301x; 1.4301x over previous
//
#include <hip/hip_runtime.h>

// Ultimus: out = x + softmax((x@Kw+Kb)@(x@Qw+Qb)^T / sqrt(8)) @ (x@Vw+Vb) @ Zw + Zb
// N=8192, D_IN=48, D_ATTN=8, fp32 in/out.
//
// R5 = R4 minus the VGPR cap. R4's __launch_bounds__(256,4) clamped to 64
// VGPRs and spilled the 72-register accumulator file to scratch
// (WRITE_SIZE 260 MB/dispatch, attn 104 us). The accumulators MUST be
// register-resident: plain __launch_bounds__(256), ~3 waves/SIMD.
//
//  - Bound-softmax (Cauchy-Schwarz row bound) => fixed per-row exponent shift,
//    partials over disjoint j-chunks combine by pure addition.
//  - attn waves fully independent: no LDS, no __syncthreads in the hot loop.
//  - f16 storage + v_dot2_f32_f16: QK dot, l-sum, p*v all as 2-way f16 dots
//    with fp32 accumulators.
//
// ws layout (floats):
//   [0, 32768)        Xksf16[8192]  row-major, 8 f16/row (k * log2e/sqrt(8))
//   [32768, 65536)    Qf16[8192]    row-major, 8 f16/row
//   [65536, 98304)    Vf16          pair-interleaved: pair p=(j=2p,2p+1),
//                                   dword (p*8+c) = half2(V[2p][c], V[2p+1][c])
//   [98304]           qmax2 bits    max_j ||q_j||^2 fp32 (uint-bits atomicMax)
//   [98560, +786432)  part[8][8192][12]  per-chunk partials acc[0:8], l at [8]

#define PART_OFF 98560

typedef _Float16 f16x2 __attribute__((ext_vector_type(2)));

union HU { unsigned u; f16x2 h; };

static __device__ __forceinline__ unsigned pku(float a, float b) {
    auto v = __builtin_amdgcn_cvt_pkrtz(a, b);   // __fp16 vec2
    union { decltype(v) v2; unsigned u; } t;
    t.v2 = v;
    return t.u;
}
static __device__ __forceinline__ f16x2 asH2(unsigned u) {
    HU t; t.u = u; return t.h;
}
static __device__ __forceinline__ float fdot2(f16x2 a, f16x2 b, float c) {
#if __has_builtin(__builtin_amdgcn_fdot2)
    return __builtin_amdgcn_fdot2(a, b, c, false);
#else
    return fmaf((float)a.x, (float)b.x, fmaf((float)a.y, (float)b.y, c));
#endif
}

__global__ __launch_bounds__(256) void proj_kernel(
    const float* __restrict__ x,
    const float* __restrict__ Kw, const float* __restrict__ Kb,
    const float* __restrict__ Qw, const float* __restrict__ Qb,
    const float* __restrict__ Vw, const float* __restrict__ Vb,
    unsigned* __restrict__ Xksf16, unsigned* __restrict__ Qf16,
    unsigned* __restrict__ Vf16, unsigned int* __restrict__ qmax2_bits)
{
    __shared__ float xs[32 * 49];     // +1 pad
    __shared__ float wAll[3 * 388];   // stride 388 (mod 32 = 4) spreads 3 mats
    __shared__ float bs[24];
    __shared__ float outv[32][25];    // 24 cols + pad
    const int tid = threadIdx.x;
    const int r0 = blockIdx.x * 32;

    for (int i = tid; i < 1536; i += 256) {
        int r = i / 48, c = i - r * 48;
        xs[r * 49 + c] = x[r0 * 48 + i];
    }
    for (int i = tid; i < 384; i += 256) {
        wAll[i]       = Kw[i];
        wAll[388 + i] = Qw[i];
        wAll[776 + i] = Vw[i];
    }
    if (tid < 8)       bs[tid] = Kb[tid];
    else if (tid < 16) bs[tid] = Qb[tid - 8];
    else if (tid < 24) bs[tid] = Vb[tid - 16];
    __syncthreads();

    // thread = (row rl, col-group g): cols 3g..3g+2 of row r0+rl
    const int rl = tid >> 3;
    const int g  = tid & 7;
    const int c0 = 3 * g;
    const float* xr = &xs[rl * 49];
    const float* w0 = &wAll[((c0 + 0) >> 3) * 388 + ((c0 + 0) & 7)];
    const float* w1 = &wAll[((c0 + 1) >> 3) * 388 + ((c0 + 1) & 7)];
    const float* w2 = &wAll[((c0 + 2) >> 3) * 388 + ((c0 + 2) & 7)];
    float a0 = bs[c0], a1 = bs[c0 + 1], a2 = bs[c0 + 2];
    #pragma unroll
    for (int k = 0; k < 48; k++) {
        const float xv = xr[k];
        a0 = fmaf(xv, w0[k * 8], a0);
        a1 = fmaf(xv, w1[k * 8], a1);
        a2 = fmaf(xv, w2[k * 8], a2);
    }
    outv[rl][c0] = a0; outv[rl][c0 + 1] = a1; outv[rl][c0 + 2] = a2;
    __syncthreads();

    const float kscale = 0.51008732149f;  // (1/sqrt(8)) * log2(e)
    if (tid < 32) {                       // K rows, f16 packed, pre-scaled
        uint4 o;
        o.x = pku(outv[tid][0] * kscale, outv[tid][1] * kscale);
        o.y = pku(outv[tid][2] * kscale, outv[tid][3] * kscale);
        o.z = pku(outv[tid][4] * kscale, outv[tid][5] * kscale);
        o.w = pku(outv[tid][6] * kscale, outv[tid][7] * kscale);
        ((uint4*)Xksf16)[r0 + tid] = o;
    } else if (tid < 64) {                // Q rows, f16 packed
        const int r = tid - 32;
        uint4 o;
        o.x = pku(outv[r][8],  outv[r][9]);
        o.y = pku(outv[r][10], outv[r][11]);
        o.z = pku(outv[r][12], outv[r][13]);
        o.w = pku(outv[r][14], outv[r][15]);
        ((uint4*)Qf16)[r0 + r] = o;
    } else if (tid < 192) {               // V pair-interleaved
        const int t2 = tid - 64;
        const int p = t2 >> 3, c = t2 & 7;
        Vf16[(blockIdx.x * 16 + p) * 8 + c] =
            pku(outv[2 * p][16 + c], outv[2 * p + 1][16 + c]);
    } else if (tid < 224) {               // qmax over fp32 q (lanes 0..31 of wave 3)
        const int r = tid - 192;
        float n2 = 0.f;
        #pragma unroll
        for (int c = 0; c < 8; c++) n2 = fmaf(outv[r][8 + c], outv[r][8 + c], n2);
        #pragma unroll
        for (int off = 16; off > 0; off >>= 1)
            n2 = fmaxf(n2, __shfl_xor(n2, off, 64));
        if (r == 0) atomicMax(qmax2_bits, __float_as_uint(n2));  // n2>=0: bit order ok
    }
}

__global__ __launch_bounds__(256) void attn_kernel(
    const unsigned* __restrict__ Xksf16, const unsigned* __restrict__ Qf16,
    const unsigned* __restrict__ Vf16,
    const unsigned int* __restrict__ qmax2_bits,
    float* __restrict__ part)
{
    const int tid   = threadIdx.x;
    const int wave  = tid >> 6, lane = tid & 63;
    const int rg    = blockIdx.x & 255;   // 32-row group
    const int chunk = blockIdx.x >> 8;    // j-chunk of 1024 (8 chunks)
    const int rw0   = rg * 32 + wave * 8;

    const float qmax2 = __uint_as_float(*qmax2_bits);

    f16x2 k2[8][4];
    float sinit[8], l[8], acc[8][8];
    #pragma unroll
    for (int r = 0; r < 8; r++) {
        const uint4 kv = ((const uint4*)Xksf16)[rw0 + r];
        k2[r][0] = asH2(kv.x); k2[r][1] = asH2(kv.y);
        k2[r][2] = asH2(kv.z); k2[r][3] = asH2(kv.w);
        float kn2 = fdot2(k2[r][0], k2[r][0], 0.f);
        kn2 = fdot2(k2[r][1], k2[r][1], kn2);
        kn2 = fdot2(k2[r][2], k2[r][2], kn2);
        kn2 = fdot2(k2[r][3], k2[r][3], kn2);
        sinit[r] = -sqrtf(kn2 * qmax2);   // |s| <= ||k_r||*max||q||: p in (0,~1]
        l[r] = 0.f;
        #pragma unroll
        for (int c = 0; c < 8; c++) acc[r][c] = 0.f;
    }

    const f16x2 one2 = asH2(pku(1.f, 1.f));
    const uint4* Q4 = (const uint4*)Qf16;   // idx = j
    const uint4* V4 = (const uint4*)Vf16;   // pair p -> uint4 idx 2p, 2p+1

    const int P0 = chunk * 512 + lane;      // this lane's first j-pair
    #pragma unroll 2
    for (int s = 0; s < 8; s++) {
        const int p = P0 + s * 64;
        const uint4 qa = Q4[2 * p];
        const uint4 qb = Q4[2 * p + 1];
        const uint4 va = V4[2 * p];
        const uint4 vb = V4[2 * p + 1];
        f16x2 qa2[4] = {asH2(qa.x), asH2(qa.y), asH2(qa.z), asH2(qa.w)};
        f16x2 qb2[4] = {asH2(qb.x), asH2(qb.y), asH2(qb.z), asH2(qb.w)};
        f16x2 v2[8]  = {asH2(va.x), asH2(va.y), asH2(va.z), asH2(va.w),
                        asH2(vb.x), asH2(vb.y), asH2(vb.z), asH2(vb.w)};
        #pragma unroll
        for (int r = 0; r < 8; r++) {
            float s0 = fdot2(k2[r][0], qa2[0], sinit[r]);
            s0 = fdot2(k2[r][1], qa2[1], s0);
            s0 = fdot2(k2[r][2], qa2[2], s0);
            s0 = fdot2(k2[r][3], qa2[3], s0);
            float s1 = fdot2(k2[r][0], qb2[0], sinit[r]);
            s1 = fdot2(k2[r][1], qb2[1], s1);
            s1 = fdot2(k2[r][2], qb2[2], s1);
            s1 = fdot2(k2[r][3], qb2[3], s1);
            const f16x2 ph = asH2(pku(__builtin_amdgcn_exp2f(s0),
                                      __builtin_amdgcn_exp2f(s1)));
            l[r] = fdot2(ph, one2, l[r]);
            acc[r][0] = fdot2(ph, v2[0], acc[r][0]);
            acc[r][1] = fdot2(ph, v2[1], acc[r][1]);
            acc[r][2] = fdot2(ph, v2[2], acc[r][2]);
            acc[r][3] = fdot2(ph, v2[3], acc[r][3]);
            acc[r][4] = fdot2(ph, v2[4], acc[r][4]);
            acc[r][5] = fdot2(ph, v2[5], acc[r][5]);
            acc[r][6] = fdot2(ph, v2[6], acc[r][6]);
            acc[r][7] = fdot2(ph, v2[7], acc[r][7]);
        }
    }

    // 64-lane butterfly sum; shared per-row exponent => pure adds
    #pragma unroll
    for (int m = 1; m < 64; m <<= 1) {
        #pragma unroll
        for (int r = 0; r < 8; r++) {
            l[r] += __shfl_xor(l[r], m, 64);
            #pragma unroll
            for (int c = 0; c < 8; c++) acc[r][c] += __shfl_xor(acc[r][c], m, 64);
        }
    }
    if (lane == 0) {
        float* pr = part + ((size_t)chunk * 8192 + rw0) * 12;
        #pragma unroll
        for (int r = 0; r < 8; r++) {
            #pragma unroll
            for (int c = 0; c < 8; c++) pr[r * 12 + c] = acc[r][c];
            pr[r * 12 + 8] = l[r];
        }
    }
}

__global__ __launch_bounds__(256) void finish_kernel(
    const float* __restrict__ x,
    const float* __restrict__ Zw, const float* __restrict__ Zb,
    const float* __restrict__ part, float* __restrict__ out)
{
    __shared__ float Zs[128 * 9];
    __shared__ float zw_s[384];
    __shared__ float zb_s[48];
    const int tid = threadIdx.x;
    const int r0 = blockIdx.x * 128;

    for (int i = tid; i < 384; i += 256) zw_s[i] = Zw[i];
    if (tid < 48) zb_s[tid] = Zb[tid];

    if (tid < 128) {
        const int row = r0 + tid;
        float a[9];
        #pragma unroll
        for (int c = 0; c < 9; c++) a[c] = 0.f;
        #pragma unroll
        for (int ch = 0; ch < 8; ch++) {
            const float* p = part + ((size_t)ch * 8192 + row) * 12;
            #pragma unroll
            for (int c = 0; c < 9; c++) a[c] += p[c];
        }
        const float inv = 1.0f / a[8];
        #pragma unroll
        for (int c = 0; c < 8; c++) Zs[tid * 9 + c] = a[c] * inv;
    }
    __syncthreads();

    for (int e = tid; e < 128 * 48; e += 256) {
        const int r = e / 48, c = e - r * 48;
        float o = x[r0 * 48 + e] + zb_s[c];
        #pragma unroll
        for (int k = 0; k < 8; k++) o = fmaf(Zs[r * 9 + k], zw_s[k * 48 + c], o);
        out[r0 * 48 + e] = o;
    }
}

extern "C" void kernel_launch(void* const* d_in, const int* in_sizes, int n_in,
                              void* d_out, int out_size, void* d_ws, size_t ws_size,
                              hipStream_t stream) {
    const float* x  = (const float*)d_in[0];
    const float* Kw = (const float*)d_in[1];
    const float* Kb = (const float*)d_in[2];
    const float* Qw = (const float*)d_in[3];
    const float* Qb = (const float*)d_in[4];
    const float* Vw = (const float*)d_in[5];
    const float* Vb = (const float*)d_in[6];
    const float* Zw = (const float*)d_in[7];
    const float* Zb = (const float*)d_in[8];
    float* out = (float*)d_out;

    float* ws = (float*)d_ws;
    unsigned* Xksf16 = (unsigned*)ws;
    unsigned* Qf16   = (unsigned*)(ws + 32768);
    unsigned* Vf16   = (unsigned*)(ws + 65536);
    unsigned int* qmax2_bits = (unsigned int*)(ws + 98304);
    float* part = ws + PART_OFF;

    (void)hipMemsetAsync(qmax2_bits, 0, sizeof(unsigned int), stream);
    proj_kernel<<<256, 256, 0, stream>>>(x, Kw, Kb, Qw, Qb, Vw, Vb,
                                         Xksf16, Qf16, Vf16, qmax2_bits);
    attn_kernel<<<2048, 256, 0, stream>>>(Xksf16, Qf16, Vf16, qmax2_bits, part);
    finish_kernel<<<64, 256, 0, stream>>>(x, Zw, Zb, part, out);
}